// Round 6
// baseline (106.104 us; speedup 1.0000x reference)
//
#include <hip/hip_runtime.h>

#define B_   64
#define H_   128
#define W_   2048
#define HW_  (H_ * W_)        // 262144
#define OH_  128
#define OW_  2048

// OpenBLAS sgemm emulation — SkylakeX-class parameters (Zen4/5 host with
// AVX512 routes to SKX kernels in modern OpenBLAS):
//   SGEMM_DEFAULT_Q = 320. K-partition (driver/level3/level3.c):
//     min_l = K-ls; if (min_l >= 2Q) Q; else if (min_l > Q) (min_l+1)/2
//   K = 262144: blocks 0..817 len 320; remaining 384 -> 192 + 192.
//     blk 818: off 261760 len 192; blk 819: off 261952 len 192.
//   Micro-kernels (m4 + m2 tails, asm or masked C): per C element a SINGLE
//   sequential FMA chain over k within each block. Cross-block: C += S_blk
//   ascending, beta=0 first block. [r3/r4 refuted Haswell Q=384; r5 refuted
//   even/odd m2 (== CR bits == r2)]
#define QBLK 320
#define NBLK 820
#define BPG  4                            // K-blocks per workgroup
#define NGRP (NBLK / BPG)                 // 205 exactly

__device__ __forceinline__ int blk_off(int blk) {
    if (blk <= 818) return blk * QBLK;    // 818*320 = 261760
    return 261952;                        // blk 819
}
__device__ __forceinline__ int blk_len(int blk) {
    return (blk < 818) ? 320 : 192;
}

// ---------------------------------------------------------------------------
// K1: per-(b, K-block) sequential-FMA partial sums.
// Lane = (q = K-block within group, b = batch). w panel staged to LDS
// (wave-uniform reads -> broadcast). x streamed as float4 per lane.
// ---------------------------------------------------------------------------
__global__ __launch_bounds__(256)
void st_block_sums(const float* __restrict__ x, const float* __restrict__ w,
                   float* __restrict__ part)
{
#pragma clang fp contract(off)
    __shared__ float4 wl4[BPG * QBLK * 6 / 4];   // 1920 float4 = 30720 B
    float* wl = (float*)wl4;
    const int g   = blockIdx.x;
    const int tid = threadIdx.x;

    const int row0  = blk_off(g * BPG);
    const int wbase = row0 * 6;
    const int nf4   = BPG * QBLK * 6 / 4;        // 1920
    for (int f4i = tid; f4i < nf4; f4i += 256) {
        const int fi = wbase + f4i * 4;
        float4 v = make_float4(0.f, 0.f, 0.f, 0.f);
        if (fi + 3 < HW_ * 6) v = *(const float4*)(w + fi);
        wl4[f4i] = v;
    }
    __syncthreads();

    const int q   = tid >> 6;
    const int b   = tid & 63;
    const int blk = g * BPG + q;                 // < 820 always (205*4)

    const int off = blk_off(blk);
    const int len = blk_len(blk);                // 320 or 192, both %4==0
    const float* __restrict__ xp = x + (size_t)b * HW_ + (size_t)off;
    const float* __restrict__ wp = wl + (size_t)(off - row0) * 6;

    // One sequential FMA chain per C element (j=0..5), k ascending.
    float a0 = 0.f, a1 = 0.f, a2 = 0.f, a3 = 0.f, a4 = 0.f, a5 = 0.f;
    const int nt4 = len >> 2;
    for (int t4 = 0; t4 < nt4; ++t4) {
        const float4 xv = *(const float4*)(xp + t4 * 4);
        const float* wr = wp + t4 * 24;
        a0 = fmaf(xv.x, wr[ 0], a0); a1 = fmaf(xv.x, wr[ 1], a1);
        a2 = fmaf(xv.x, wr[ 2], a2); a3 = fmaf(xv.x, wr[ 3], a3);
        a4 = fmaf(xv.x, wr[ 4], a4); a5 = fmaf(xv.x, wr[ 5], a5);
        a0 = fmaf(xv.y, wr[ 6], a0); a1 = fmaf(xv.y, wr[ 7], a1);
        a2 = fmaf(xv.y, wr[ 8], a2); a3 = fmaf(xv.y, wr[ 9], a3);
        a4 = fmaf(xv.y, wr[10], a4); a5 = fmaf(xv.y, wr[11], a5);
        a0 = fmaf(xv.z, wr[12], a0); a1 = fmaf(xv.z, wr[13], a1);
        a2 = fmaf(xv.z, wr[14], a2); a3 = fmaf(xv.z, wr[15], a3);
        a4 = fmaf(xv.z, wr[16], a4); a5 = fmaf(xv.z, wr[17], a5);
        a0 = fmaf(xv.w, wr[18], a0); a1 = fmaf(xv.w, wr[19], a1);
        a2 = fmaf(xv.w, wr[20], a2); a3 = fmaf(xv.w, wr[21], a3);
        a4 = fmaf(xv.w, wr[22], a4); a5 = fmaf(xv.w, wr[23], a5);
    }

    float* o = part + ((size_t)blk * 64 + b) * 6;
    o[0] = a0; o[1] = a1; o[2] = a2; o[3] = a3; o[4] = a4; o[5] = a5;
}

// ---------------------------------------------------------------------------
// K1b: ordered cross-block accumulation (ascending), + b_loc in fp32.
// ---------------------------------------------------------------------------
__global__ __launch_bounds__(384)
void st_theta_final(const float* __restrict__ part, const float* __restrict__ bl,
                    float* __restrict__ theta)
{
#pragma clang fp contract(off)
    const int i = threadIdx.x;
    if (i >= 384) return;
    const int b = i / 6, j = i % 6;
    float acc = part[(size_t)b * 6 + j];              // S_0 (beta=0)
    for (int blk = 1; blk < NBLK; ++blk)
        acc = acc + part[((size_t)blk * 64 + b) * 6 + j];
    theta[i] = acc + bl[j];
}

// ---------------------------------------------------------------------------
// K2: bilinear sampler — faithful fp32 numpy replay downstream of theta.
// (unchanged; verified against the reference formulas)
// ---------------------------------------------------------------------------
__global__ __launch_bounds__(256)
void st_sample(const float* __restrict__ x, const float* __restrict__ theta,
               float* __restrict__ out)
{
#pragma clang fp contract(off)
    __shared__ float th[6];
    const int blk = blockIdx.x;
    const int b   = blk >> 8;          // 256 blocks per batch
    const int rem = blk & 255;
    const int yo  = rem >> 1;
    const int seg = rem & 1;

    if (threadIdx.x < 6) th[threadIdx.x] = theta[b * 6 + threadIdx.x];
    __syncthreads();

    const float t00 = th[0], t01 = th[1], t02 = th[2];
    const float t10 = th[3], t11 = th[4], t12 = th[5];

    const int xo0 = seg * 1024 + threadIdx.x * 4;
    const float* __restrict__ img = x + (size_t)b * HW_;
    const float yof = (float)yo;

    const float cx1 = t01 * yof;
    const float cy1 = t11 * yof;

    float4 o;
    float* op = (float*)&o;
#pragma unroll
    for (int i = 0; i < 4; ++i) {
        const float xof = (float)(xo0 + i);
        const float px  = t00 * xof;
        const float sx  = px + cx1;
        const float xq  = sx + t02;
        const float py  = t10 * xof;
        const float sy  = py + cy1;
        const float yq  = sy + t12;

        const int x0 = (int)floorf(xq);
        const int y0 = (int)floorf(yq);
        const int x0c = min(max(x0,     0), W_ - 1);
        const int x1c = min(max(x0 + 1, 0), W_ - 1);
        const int y0c = min(max(y0,     0), H_ - 1);
        const int y1c = min(max(y0 + 1, 0), H_ - 1);

        const float x0f = (float)x0c, x1f = (float)x1c;
        const float y0f = (float)y0c, y1f = (float)y1c;

        const float gx = x1f - xq;
        const float fx = xq - x0f;
        const float gy = y1f - yq;
        const float fy = yq - y0f;

        const float wa = gx * gy;
        const float wb = gx * fy;
        const float wc = fx * gy;
        const float wd = fx * fy;

        const float* r0 = img + y0c * W_;
        const float* r1 = img + y1c * W_;
        const float Ia = r0[x0c];
        const float Ib = r1[x0c];
        const float Ic = r0[x1c];
        const float Id = r1[x1c];

        const float pa = wa * Ia;
        const float pb = wb * Ib;
        const float s1 = pa + pb;
        const float pc = wc * Ic;
        const float s2 = s1 + pc;
        const float pd = wd * Id;
        op[i] = s2 + pd;
    }

    const size_t oidx = ((size_t)b * OH_ + yo) * OW_ + xo0;
    *(float4*)(out + oidx) = o;
}

extern "C" void kernel_launch(void* const* d_in, const int* in_sizes, int n_in,
                              void* d_out, int out_size, void* d_ws, size_t ws_size,
                              hipStream_t stream)
{
    const float* x  = (const float*)d_in[0];
    const float* w  = (const float*)d_in[1];
    const float* bl = (const float*)d_in[2];
    float* out = (float*)d_out;

    // d_out doubles as the 1.26 MB block-sum scratch (820*64*6 floats), fully
    // consumed by st_theta_final before st_sample overwrites every element.
    float* part  = (float*)d_out;
    float* theta = (float*)d_ws;    // 384 floats

    st_block_sums<<<NGRP, 256, 0, stream>>>(x, w, part);
    st_theta_final<<<1, 384, 0, stream>>>(part, bl, theta);
    st_sample<<<B_ * OH_ * 2, 256, 0, stream>>>(x, theta, out);
}

// Round 8
// 98.189 us; speedup vs baseline: 1.0806x; 1.0806x over previous
//
#include <hip/hip_runtime.h>

#define B_   64
#define H_   128
#define W_   2048
#define HW_  (H_ * W_)        // 262144
#define OH_  128
#define OW_  2048

typedef float nfloat4 __attribute__((ext_vector_type(4)));

// OpenBLAS sgemm emulation — SkylakeX params (VERIFIED bit-exact in round 6):
//   SGEMM_DEFAULT_Q = 320; K = 262144 -> blocks 0..817 len 320,
//   blk 818: off 261760 len 192; blk 819: off 261952 len 192.
//   Per C element: single sequential FMA chain over k within each block;
//   cross-block C += S_blk ascending; + b_loc in fp32.
// !!! The per-(blk,b,j) fmaf sequence and the K2 fp32 replay are bit-locked —
// !!! optimizations may only change load mechanics / parallel mapping.
#define QBLK 320
#define NBLK 820

__device__ __forceinline__ int blk_off(int blk) {
    if (blk <= 818) return blk * QBLK;    // 818*320 = 261760
    return 261952;                        // blk 819
}
__device__ __forceinline__ int blk_len(int blk) {
    return (blk < 818) ? 320 : 192;
}

// ---------------------------------------------------------------------------
// K1: per-(b, K-block) sequential-FMA partial sums.
// Grid: 1640 blocks = (kblk 0..819) x (bhalf 0..1); 192 threads = 6 j x 32 b.
// x-chunk [32 b][<=320 k] staged in LDS (stride 324 floats: 16B-aligned,
// %32==4 -> spread start banks); w staged transposed wt[j][k].
// Each thread: ONE (b,j) chain, k ascending, groups of 4 via float4 —
// the exact fmaf sequence of the verified round-6 kernel.
// ---------------------------------------------------------------------------
#define XPAD 324
__global__ __launch_bounds__(192)
void st_block_sums(const float* __restrict__ x, const float* __restrict__ w,
                   float* __restrict__ part)
{
    __shared__ float xs[32 * XPAD];      // 41472 B
    __shared__ float wt[6 * QBLK];       //  7680 B   (total 48.0 KB)

    const int kblk  = blockIdx.x >> 1;
    const int bhalf = blockIdx.x & 1;
    const int tid   = threadIdx.x;

    const int off = blk_off(kblk);
    const int len = blk_len(kblk);               // 320 or 192
    const int nt4 = len >> 2;                    // 80 or 48

    // stage x: 32 rows x nt4 float4, coalesced per row
    {
        const int b0 = bhalf * 32;
        float4* xs4 = (float4*)xs;               // row stride 81 float4
        for (int idx = tid; idx < 32 * 80; idx += 192) {
            const int b  = idx / 80;
            const int f4 = idx % 80;
            if (f4 < nt4) {
                const float4 v = *(const float4*)(x + (size_t)(b0 + b) * HW_ + off + f4 * 4);
                xs4[b * (XPAD / 4) + f4] = v;
            }
        }
    }
    // stage w transposed: wt[j][k] = w[(off+k)*6 + j]; linear coalesced read
    for (int e = tid; e < 6 * len; e += 192) {
        const float v = w[(size_t)off * 6 + e];
        const int k = e / 6, j = e % 6;
        wt[j * QBLK + k] = v;
    }
    __syncthreads();

    const int j = tid >> 5;                      // 0..5
    const int b = tid & 31;
    const int bg = bhalf * 32 + b;

    const float* __restrict__ xr = xs + b * XPAD;
    const float* __restrict__ wr = wt + j * QBLK;

    float a = 0.f;
    for (int t4 = 0; t4 < nt4; ++t4) {
        const float4 xv = *(const float4*)(xr + t4 * 4);
        const float4 wv = *(const float4*)(wr + t4 * 4);
        a = fmaf(xv.x, wv.x, a);
        a = fmaf(xv.y, wv.y, a);
        a = fmaf(xv.z, wv.z, a);
        a = fmaf(xv.w, wv.w, a);
    }
    part[((size_t)kblk * 64 + bg) * 6 + j] = a;
}

// ---------------------------------------------------------------------------
// K1b: ordered cross-block accumulation (ascending), + b_loc in fp32.
// ---------------------------------------------------------------------------
__global__ __launch_bounds__(384)
void st_theta_final(const float* __restrict__ part, const float* __restrict__ bl,
                    float* __restrict__ theta)
{
#pragma clang fp contract(off)
    const int i = threadIdx.x;
    if (i >= 384) return;
    const int b = i / 6, j = i % 6;
    float acc = part[(size_t)b * 6 + j];              // S_0 (beta=0)
    for (int blk = 1; blk < NBLK; ++blk)
        acc = acc + part[((size_t)blk * 64 + b) * 6 + j];
    theta[i] = acc + bl[j];
}

// window select: e[m] = v[s+m] for m=0..4, v = {A.xyzw, B.xyzw}, s in 0..3.
// Pure bit-moves (cndmask) — no FP arithmetic.
__device__ __forceinline__ void win5(const float4 A, const float4 Bv, const int s,
                                     float& e0, float& e1, float& e2,
                                     float& e3, float& e4)
{
    const bool s1 = (s & 1) != 0;
    const bool s2 = (s & 2) != 0;
    const float v0 = A.x, v1 = A.y, v2 = A.z, v3 = A.w;
    const float v4 = Bv.x, v5 = Bv.y, v6 = Bv.z, v7 = Bv.w;
    const float w0 = s1 ? v1 : v0;
    const float w1 = s1 ? v2 : v1;
    const float w2 = s1 ? v3 : v2;
    const float w3 = s1 ? v4 : v3;
    const float w4 = s1 ? v5 : v4;
    const float w5 = s1 ? v6 : v5;
    const float w6 = s1 ? v7 : v6;
    e0 = s2 ? w2 : w0;
    e1 = s2 ? w3 : w1;
    e2 = s2 ? w4 : w2;
    e3 = s2 ? w5 : w3;
    e4 = s2 ? w6 : w4;
}

// ---------------------------------------------------------------------------
// K2: bilinear sampler — faithful fp32 numpy replay downstream of theta
// (arithmetic IDENTICAL to round 6). Loads: fast path when the 4-px group is
// interior + consecutive (4 aligned float4 + window shifts, provably the same
// values); slow path = original 16 gathers otherwise.
// ---------------------------------------------------------------------------
__global__ __launch_bounds__(256)
void st_sample(const float* __restrict__ x, const float* __restrict__ theta,
               float* __restrict__ out)
{
#pragma clang fp contract(off)
    __shared__ float th[6];
    const int blk = blockIdx.x;
    const int b   = blk >> 8;          // 256 blocks per batch
    const int rem = blk & 255;
    const int yo  = rem >> 1;
    const int seg = rem & 1;

    if (threadIdx.x < 6) th[threadIdx.x] = theta[b * 6 + threadIdx.x];
    __syncthreads();

    const float t00 = th[0], t01 = th[1], t02 = th[2];
    const float t10 = th[3], t11 = th[4], t12 = th[5];

    const int xo0 = seg * 1024 + threadIdx.x * 4;
    const float* __restrict__ img = x + (size_t)b * HW_;
    const float yof = (float)yo;

    const float cx1 = t01 * yof;
    const float cy1 = t11 * yof;

    float xq[4], yq[4];
    int x0c[4], x1c[4], y0c[4], y1c[4];
    int x0raw0 = 0;

#pragma unroll
    for (int i = 0; i < 4; ++i) {
        const float xof = (float)(xo0 + i);
        const float px  = t00 * xof;
        const float sx  = px + cx1;
        xq[i] = sx + t02;
        const float py  = t10 * xof;
        const float sy  = py + cy1;
        yq[i] = sy + t12;

        const int x0 = (int)floorf(xq[i]);
        const int y0 = (int)floorf(yq[i]);
        if (i == 0) x0raw0 = x0;
        x0c[i] = min(max(x0,     0), W_ - 1);
        x1c[i] = min(max(x0 + 1, 0), W_ - 1);
        y0c[i] = min(max(y0,     0), H_ - 1);
        y1c[i] = min(max(y0 + 1, 0), H_ - 1);
    }

    const bool fast =
        (x0raw0 >= 0) &&
        (x0c[1] == x0c[0] + 1) && (x0c[2] == x0c[0] + 2) && (x0c[3] == x0c[0] + 3) &&
        (x1c[3] == x0c[3] + 1) &&
        (y0c[1] == y0c[0]) && (y0c[2] == y0c[0]) && (y0c[3] == y0c[0]) &&
        (y1c[1] == y1c[0]) && (y1c[2] == y1c[0]) && (y1c[3] == y1c[0]);

    float Ia[4], Ib[4], Ic[4], Id[4];
    if (fast) {
        const int base = x0c[0];
        const int a0   = base & ~3;
        const int s    = base & 3;
        const float* r0 = img + y0c[0] * W_ + a0;
        const float* r1 = img + y1c[0] * W_ + a0;
        const float4 A  = *(const float4*)(r0);
        const float4 Bv = *(const float4*)(r0 + 4);
        const float4 C  = *(const float4*)(r1);
        const float4 D  = *(const float4*)(r1 + 4);
        float e0, e1, e2, e3, e4;
        win5(A, Bv, s, e0, e1, e2, e3, e4);
        Ia[0] = e0; Ia[1] = e1; Ia[2] = e2; Ia[3] = e3;
        Ic[0] = e1; Ic[1] = e2; Ic[2] = e3; Ic[3] = e4;
        win5(C, D, s, e0, e1, e2, e3, e4);
        Ib[0] = e0; Ib[1] = e1; Ib[2] = e2; Ib[3] = e3;
        Id[0] = e1; Id[1] = e2; Id[2] = e3; Id[3] = e4;
    } else {
#pragma unroll
        for (int i = 0; i < 4; ++i) {
            const float* r0 = img + y0c[i] * W_;
            const float* r1 = img + y1c[i] * W_;
            Ia[i] = r0[x0c[i]];
            Ib[i] = r1[x0c[i]];
            Ic[i] = r0[x1c[i]];
            Id[i] = r1[x1c[i]];
        }
    }

    nfloat4 o;
#pragma unroll
    for (int i = 0; i < 4; ++i) {
        const float x0f = (float)x0c[i], x1f = (float)x1c[i];
        const float y0f = (float)y0c[i], y1f = (float)y1c[i];

        const float gx = x1f - xq[i];
        const float fx = xq[i] - x0f;
        const float gy = y1f - yq[i];
        const float fy = yq[i] - y0f;

        const float wa = gx * gy;
        const float wb = gx * fy;
        const float wc = fx * gy;
        const float wd = fx * fy;

        const float pa = wa * Ia[i];
        const float pb = wb * Ib[i];
        const float s1 = pa + pb;
        const float pc = wc * Ic[i];
        const float s2 = s1 + pc;
        const float pd = wd * Id[i];
        o[i] = s2 + pd;
    }

    const size_t oidx = ((size_t)b * OH_ + yo) * OW_ + xo0;
    __builtin_nontemporal_store(o, (nfloat4*)(out + oidx));
}

extern "C" void kernel_launch(void* const* d_in, const int* in_sizes, int n_in,
                              void* d_out, int out_size, void* d_ws, size_t ws_size,
                              hipStream_t stream)
{
    const float* x  = (const float*)d_in[0];
    const float* w  = (const float*)d_in[1];
    const float* bl = (const float*)d_in[2];
    float* out = (float*)d_out;

    // d_out doubles as the 1.26 MB block-sum scratch (820*64*6 floats), fully
    // consumed by st_theta_final before st_sample overwrites every element.
    float* part  = (float*)d_out;
    float* theta = (float*)d_ws;    // 384 floats

    st_block_sums<<<NBLK * 2, 192, 0, stream>>>(x, w, part);
    st_theta_final<<<1, 384, 0, stream>>>(part, bl, theta);
    st_sample<<<B_ * OH_ * 2, 256, 0, stream>>>(x, theta, out);
}